// Round 5
// baseline (94.835 us; speedup 1.0000x reference)
//
#include <hip/hip_runtime.h>

// ADDA local attention, K=3, dilation=1, head_dim=64.
// q,k,v = [B=8, d=512, H=56, W=56] fp32 (channel-major), out = [B,H,W,512] fp32.
//
// R4 counters: latency-bound (Occ 30%, VALU 16%, HBM 26%), scalar loads,
// 32-64B store chunks. This version:
//  - thread = (4-pixel aligned quad, 8-channel group); float4 window loads
//    (1 f4 + 2 boundary dwords per row) -> ~7.7x fewer VMEM instrs per pixel
//  - lane map tid = ql*8+cg -> stores from 8 consecutive lanes form one
//    contiguous 256B line-aligned run (zero write inflation)
//  - partial logits reduced across channel groups via LDS tree
//    (layout [ql][cg][37] -> 2-way bank aliasing, free)
//  - softmax computed once per quad (cg==0), broadcast via LDS

namespace {

constexpr int HD   = 64;
constexpr int HH   = 56, WW = 56, HW = HH * WW;
constexpr int CS   = HW;            // channel stride (elements)
constexpr int DTOT = 512;
constexpr float SCALE = 0.125f;     // 64^-0.5
constexpr int QROW = WW / 4;        // 14 quads per row
constexpr int NQ   = HW / 4;        // 784 quads per plane
constexpr int QPB  = 16;            // quads per block
constexpr int NQB  = NQ / QPB;      // 49 blocks per (b,head)
constexpr int NCG  = 8;             // channel groups
constexpr int CPT  = HD / NCG;      // 8 channels per thread
constexpr int LP   = 37;            // 36 logits padded (bank-friendly)

__global__ __launch_bounds__(128)
void adda_fwd(const float* __restrict__ qg, const float* __restrict__ kg,
              const float* __restrict__ vg, float* __restrict__ outg) {
  const int qb = blockIdx.x % NQB;
  const int bh = blockIdx.x / NQB;          // b*8 + head
  const int cg = (int)threadIdx.x & (NCG - 1);
  const int ql = (int)threadIdx.x >> 3;     // 0..15
  const int quad = qb * QPB + ql;           // 0..783
  const int y  = quad / QROW;
  const int xq = quad - y * QROW;
  const int x0 = xq * 4;
  const int p  = y * WW + x0;               // 16B-aligned pixel base

  const int base = bh * (HD * HW) + cg * (CPT * HW) + p;
  const float* __restrict__ qp = qg + base;
  const float* __restrict__ kp = kg + base;
  const float* __restrict__ vp = vg + base;

  // clamped row offsets (dy=-1,0,1) and horizontal boundary offsets
  int ro[3];
#pragma unroll
  for (int r = 0; r < 3; ++r) {
    const int yy = y + r - 1;
    ro[r] = ((unsigned)yy < (unsigned)HH) ? (r - 1) * WW : 0;
  }
  const int lo = (xq > 0) ? -1 : 0;         // x0-1 (clamped)
  const int hi = (xq < QROW - 1) ? 4 : 3;   // x0+4 (clamped)

  // ---- pass 1: partial logits over this thread's 8 channels ----
  float lg[4][9];
#pragma unroll
  for (int e = 0; e < 4; ++e)
#pragma unroll
    for (int n = 0; n < 9; ++n) lg[e][n] = 0.f;

#pragma unroll
  for (int c = 0; c < CPT; ++c) {
    const float4 qv = *(const float4*)(qp + c * CS);
#pragma unroll
    for (int r = 0; r < 3; ++r) {
      const float* rowp = kp + c * CS + ro[r];
      const float4 kc = *(const float4*)rowp;
      const float  kl = rowp[lo];
      const float  kr = rowp[hi];
      // win[i] = k value at x = x0 - 1 + i
      const float win[6] = {kl, kc.x, kc.y, kc.z, kc.w, kr};
#pragma unroll
      for (int e = 0; e < 4; ++e) {
        const float qe = (&qv.x)[e];
        lg[e][r * 3 + 0] = fmaf(qe, win[e],     lg[e][r * 3 + 0]); // dx=-1
        lg[e][r * 3 + 1] = fmaf(qe, win[e + 1], lg[e][r * 3 + 1]); // dx= 0
        lg[e][r * 3 + 2] = fmaf(qe, win[e + 2], lg[e][r * 3 + 2]); // dx=+1
      }
    }
  }

  // ---- LDS tree reduce across the 8 channel groups ----
  __shared__ float part[QPB][NCG][LP];
#pragma unroll
  for (int e = 0; e < 4; ++e)
#pragma unroll
    for (int n = 0; n < 9; ++n) part[ql][cg][e * 9 + n] = lg[e][n];
  __syncthreads();

  if (cg < 4) {
#pragma unroll
    for (int i = 0; i < 36; ++i) part[ql][cg][i] += part[ql][cg + 4][i];
  }
  __syncthreads();
  if (cg < 2) {
#pragma unroll
    for (int i = 0; i < 36; ++i) part[ql][cg][i] += part[ql][cg + 2][i];
  }
  __syncthreads();

  // ---- softmax once per quad (cg==0), weights written back to part[ql][0] ----
  if (cg == 0) {
#pragma unroll
    for (int e = 0; e < 4; ++e) {
      const int xx = x0 + e;
      float lge[9];
#pragma unroll
      for (int n = 0; n < 9; ++n) {
        const int dy = n / 3 - 1, dx = n % 3 - 1;
        const bool ok = ((unsigned)(y + dy) < (unsigned)HH) &&
                        ((unsigned)(xx + dx) < (unsigned)WW);
        const float s = part[ql][0][e * 9 + n] + part[ql][1][e * 9 + n];
        lge[n] = ok ? s * SCALE : 0.f;   // zero-padded unfold: OOB logit = 0
      }
      float m = lge[0];
#pragma unroll
      for (int n = 1; n < 9; ++n) m = fmaxf(m, lge[n]);
      float sum = 0.f, ex[9];
#pragma unroll
      for (int n = 0; n < 9; ++n) { ex[n] = __expf(lge[n] - m); sum += ex[n]; }
      const float inv = 1.f / sum;
#pragma unroll
      for (int n = 0; n < 9; ++n) {
        const int dy = n / 3 - 1, dx = n % 3 - 1;
        const bool ok = ((unsigned)(y + dy) < (unsigned)HH) &&
                        ((unsigned)(xx + dx) < (unsigned)WW);
        part[ql][0][e * 9 + n] = ok ? ex[n] * inv : 0.f;  // OOB v is 0 -> drop
      }
    }
  }
  __syncthreads();

  float w[4][9];
#pragma unroll
  for (int e = 0; e < 4; ++e)
#pragma unroll
    for (int n = 0; n < 9; ++n) w[e][n] = part[ql][0][e * 9 + n];

  // ---- pass 2: weighted V over this thread's 8 channels ----
  float o[4][CPT];
#pragma unroll
  for (int e = 0; e < 4; ++e)
#pragma unroll
    for (int c = 0; c < CPT; ++c) o[e][c] = 0.f;

#pragma unroll
  for (int c = 0; c < CPT; ++c) {
#pragma unroll
    for (int r = 0; r < 3; ++r) {
      const float* rowp = vp + c * CS + ro[r];
      const float4 vc = *(const float4*)rowp;
      const float  vl = rowp[lo];
      const float  vr = rowp[hi];
      const float win[6] = {vl, vc.x, vc.y, vc.z, vc.w, vr};
#pragma unroll
      for (int e = 0; e < 4; ++e) {
        o[e][c] = fmaf(w[e][r * 3 + 0], win[e],     o[e][c]);
        o[e][c] = fmaf(w[e][r * 3 + 1], win[e + 1], o[e][c]);
        o[e][c] = fmaf(w[e][r * 3 + 2], win[e + 2], o[e][c]);
      }
    }
  }

  // ---- coalesced stores: 8 lanes (cg 0..7) form one 256B contiguous run ----
  const int b = bh >> 3, head = bh & 7;
  float* __restrict__ op0 = outg + ((long)b * HW + p) * DTOT + head * HD + cg * CPT;
#pragma unroll
  for (int e = 0; e < 4; ++e) {
    float* op = op0 + e * DTOT;
    *(float4*)(op)     = make_float4(o[e][0], o[e][1], o[e][2], o[e][3]);
    *(float4*)(op + 4) = make_float4(o[e][4], o[e][5], o[e][6], o[e][7]);
  }
}

} // namespace

extern "C" void kernel_launch(void* const* d_in, const int* in_sizes, int n_in,
                              void* d_out, int out_size, void* d_ws, size_t ws_size,
                              hipStream_t stream) {
  const float* q = (const float*)d_in[0];
  const float* k = (const float*)d_in[1];
  const float* v = (const float*)d_in[2];
  float* out = (float*)d_out;

  const int BH = in_sizes[0] / (HD * HW);  // B * 8 heads = 64
  dim3 grid(BH * NQB);
  adda_fwd<<<grid, 128, 0, stream>>>(q, k, v, out);
}